// Round 5
// baseline (620.465 us; speedup 1.0000x reference)
//
#include <hip/hip_runtime.h>

#define DD 256
#define TT 4096
#define BB 32

typedef __attribute__((ext_vector_type(8))) short short8;   // 8 bf16 (4 VGPR)
typedef __attribute__((ext_vector_type(4))) float floatx4;  // MFMA acc

// ---------- bf16 helpers (RNE via bit twiddle) ----------
__device__ __forceinline__ unsigned short f2bf(float f) {
    unsigned u = __builtin_bit_cast(unsigned, f);
    unsigned r = u + 0x7FFFu + ((u >> 16) & 1u);
    return (unsigned short)(r >> 16);
}
__device__ __forceinline__ float2 unpk(unsigned u) {
    float2 r;
    r.x = __builtin_bit_cast(float, u << 16);
    r.y = __builtin_bit_cast(float, u & 0xFFFF0000u);
    return r;
}

#define GLDS16(g, l)                                                        \
    __builtin_amdgcn_global_load_lds(                                       \
        (const __attribute__((address_space(1))) void*)(g),                 \
        (__attribute__((address_space(3))) void*)(l), 16, 0, 0)

// ======================= X prep: fp32 -> bf16 ==============================
__global__ __launch_bounds__(256)
void prep_x_kernel(const float* __restrict__ X, unsigned short* __restrict__ Xh)
{
    size_t i = ((size_t)blockIdx.x * 256 + threadIdx.x) * 8;
    float4 a = *(const float4*)(X + i);
    float4 b = *(const float4*)(X + i + 4);
    short8 o;
    o[0] = (short)f2bf(a.x); o[1] = (short)f2bf(a.y);
    o[2] = (short)f2bf(a.z); o[3] = (short)f2bf(a.w);
    o[4] = (short)f2bf(b.x); o[5] = (short)f2bf(b.y);
    o[6] = (short)f2bf(b.z); o[7] = (short)f2bf(b.w);
    *(short8*)(Xh + i) = o;
}

// ======================= weight prep: bf16 + transpose =====================
// Wt[z][n][k] bf16 (single term; lo-part dropped).
__global__ void prep_w_kernel(const float* __restrict__ Wq,
                              const float* __restrict__ Wk,
                              const float* __restrict__ Wv,
                              unsigned short* __restrict__ Wt)
{
    const int z = blockIdx.y;
    const int k = blockIdx.x;
    const int n = threadIdx.x;
    const float* W = (z == 0) ? Wq : (z == 1) ? Wk : Wv;
    Wt[(size_t)z * 65536 + (size_t)n * 256 + k] = f2bf(W[k * 256 + n]);
}

// ======================= QKV GEMM: C = xh@Wh (bf16 MFMA) ===================
// 128x128 tile, BK=64 (4 K-iters, halved barrier count). XOR-swizzled LDS:
// global source chunk permuted so global_load_lds dest stays contiguous while
// ds_read_b128 is conflict-free (2-way max).
__global__ __launch_bounds__(256, 3)
void qkv_mfma_kernel(const unsigned short* __restrict__ Xh,
                     const unsigned short* __restrict__ Wt,
                     const float* __restrict__ bq, const float* __restrict__ bk,
                     const float* __restrict__ bv,
                     unsigned short* __restrict__ Q, unsigned short* __restrict__ Kp,
                     unsigned short* __restrict__ V)
{
    const int z = blockIdx.z;
    const unsigned short* Wz = Wt + (size_t)z * 65536;
    const float* bias = (z == 0) ? bq : (z == 1) ? bk : bv;
    unsigned short* Y = (z == 0) ? Q : (z == 1) ? Kp : V;

    __shared__ __align__(16) unsigned char smem[32768];
    unsigned short* Asm = (unsigned short*)smem;            // [128][64] bf16, 16 KB
    unsigned short* Bsm = (unsigned short*)(smem + 16384);  // [128][64] bf16, 16 KB

    const int tid = threadIdx.x;
    const int lane = tid & 63, wave = tid >> 6;
    const int wm = wave & 1, wn = wave >> 1;
    const int l15 = lane & 15, lq = lane >> 4;
    const int col0 = blockIdx.x * 128;
    const size_t row0 = (size_t)blockIdx.y * 128;

    floatx4 acc[4][4];
    #pragma unroll
    for (int i = 0; i < 4; ++i)
        #pragma unroll
        for (int j = 0; j < 4; ++j)
            acc[i][j] = (floatx4){0.f, 0.f, 0.f, 0.f};

    for (int k0 = 0; k0 < 256; k0 += 64) {
        __syncthreads();
        // A: 128 rows x 64 k = 1024 x 16B chunks; source-chunk XOR swizzle
        #pragma unroll
        for (int it = 0; it < 4; ++it) {
            int flat = it * 256 + tid;
            int m = flat >> 3, c = flat & 7;
            GLDS16(Xh + (row0 + m) * 256 + k0 + ((c ^ (m & 7)) * 8), Asm + flat * 8);
        }
        #pragma unroll
        for (int it = 0; it < 4; ++it) {
            int flat = it * 256 + tid;
            int n = flat >> 3, c = flat & 7;
            GLDS16(Wz + (size_t)(col0 + n) * 256 + k0 + ((c ^ (n & 7)) * 8), Bsm + flat * 8);
        }
        __syncthreads();

        short8 a[4][2];
        #pragma unroll
        for (int mt = 0; mt < 4; ++mt)
            #pragma unroll
            for (int kk = 0; kk < 2; ++kk) {
                int row = wm * 64 + mt * 16 + l15;
                a[mt][kk] = *(const short8*)(Asm + row * 64 + (((kk * 4 + lq) ^ (l15 & 7)) * 8));
            }
        #pragma unroll
        for (int kk = 0; kk < 2; ++kk)
            #pragma unroll
            for (int nt = 0; nt < 4; ++nt) {
                int rn = wn * 64 + nt * 16 + l15;
                short8 b = *(const short8*)(Bsm + rn * 64 + (((kk * 4 + lq) ^ (l15 & 7)) * 8));
                #pragma unroll
                for (int mt = 0; mt < 4; ++mt)
                    acc[mt][nt] = __builtin_amdgcn_mfma_f32_16x16x32_bf16(a[mt][kk], b, acc[mt][nt], 0, 0, 0);
            }
    }

    // ---- epilogue: bias + bf16 pack via per-wave LDS transpose ----
    __syncthreads();
    unsigned short* Cs = (unsigned short*)(smem + wave * 8192); // [64][64] bf16
    #pragma unroll
    for (int nt = 0; nt < 4; ++nt) {
        float bv_ = bias[col0 + wn * 64 + nt * 16 + l15];
        #pragma unroll
        for (int mt = 0; mt < 4; ++mt)
            #pragma unroll
            for (int r = 0; r < 4; ++r) {
                int row = mt * 16 + lq * 4 + r;
                Cs[row * 64 + nt * 16 + l15] = f2bf(acc[mt][nt][r] + bv_);
            }
    }
    #pragma unroll
    for (int p = 0; p < 8; ++p) {
        int row = p * 8 + (lane >> 3);
        float4 d = *(const float4*)(Cs + row * 64 + (lane & 7) * 8);
        *(float4*)(Y + (row0 + wm * 64 + row) * 256 + col0 + wn * 64 + (lane & 7) * 8) = d;
    }
}

// ======================= fused 3-scale attention ===========================
__device__ __forceinline__ float gelu_exact(float x) {
    return 0.5f * x * (1.0f + erff(x * 0.70710678118654752f));
}
__device__ __forceinline__ void addu4(uint4 d, float* f) {
    float2 t;
    t = unpk(d.x); f[0] += t.x; f[1] += t.y;
    t = unpk(d.y); f[2] += t.x; f[3] += t.y;
    t = unpk(d.z); f[4] += t.x; f[5] += t.y;
    t = unpk(d.w); f[6] += t.x; f[7] += t.y;
}

#define SPAN 32
#define NROW 34            // span + 2 leading ghost rows
#define STR  264           // bf16 LDS row stride
#define PLQ  (NROW * STR)  // one plane, elems

// Block = (span s, batch b). 256 threads = 64 units x 4 lanes.
// Unit = (scale, window, head); unit-lane covers 16 of the head's 64 feats.
// q,k staged in LDS (multi-read); v read from global (L1/L2-resident span).
__global__ __launch_bounds__(256, 4)
void attn_fused_kernel(const unsigned short* __restrict__ Q,
                       const unsigned short* __restrict__ K,
                       const unsigned short* __restrict__ V,
                       float* __restrict__ acc)
{
    __shared__ __align__(16) unsigned char smem[2 * PLQ * 2];  // 35,904 B
    unsigned short* qks = (unsigned short*)smem;               // [2][NROW][STR]
    float* scratch = (float*)smem;                             // [16][256] overlay

    const int tid = threadIdx.x;
    const int s = blockIdx.x;          // span within batch (0..127)
    const int b = blockIdx.y;
    const int r0 = s * SPAN;
    const unsigned short* vsrc = V + (size_t)b * TT * DD;

    // ---- load phase: q,k planes, 34 rows x 512 B each ----
    #pragma unroll
    for (int t = 0; t < 2; ++t) {
        const unsigned short* src = ((t == 0) ? Q : K) + (size_t)b * TT * DD;
        #pragma unroll
        for (int it = 0; it < 5; ++it) {
            int flat = it * 256 + tid;
            if (flat < NROW * 32) {
                int row = flat >> 5, c = flat & 31;
                int g = r0 - 2 + row;
                g = (g < 0) ? 0 : g;
                uint4 d = *(const uint4*)(src + (size_t)g * DD + c * 8);
                *(uint4*)(qks + t * PLQ + row * STR + c * 8) = d;
            }
        }
    }
    __syncthreads();

    // ---- unit decode (waves are scale-uniform) ----
    const int slot = tid >> 2, lq = tid & 3;
    const int head = slot & 3, u = slot >> 2;     // u = 0..15
    int ksize, LEN, w; bool active = true;
    if (u < 8)       { ksize = 1; LEN = 4096; w = s * 8 + u; }
    else if (u < 12) { ksize = 2; LEN = 2049; w = s * 4 + (u - 8); }
    else if (u < 14) { ksize = 4; LEN = 1025; w = s * 2 + (u - 12); }
    else if (u == 14){ ksize = 2; LEN = 2049; w = 512; active = (s == 127); }
    else             { ksize = 4; LEN = 1025; w = 256; active = (s == 127); }

    const int f0 = head * 64 + lq * 16;
    float accL[16];
    #pragma unroll
    for (int i = 0; i < 16; ++i) accL[i] = 0.f;

    if (active) {
        int ridx[4][4];   // LDS row idx for q/k
        int rg[4][4];     // global row for v
        float cw[4]; bool val[4];
        for (int i = 0; i < 4; ++i) {
            int p = w * 4 + i;
            val[i] = (p < LEN);
            int pc = val[i] ? p : 0;
            int r[4] = {0, 0, 0, 0};
            if (ksize == 1) { r[0] = pc; }
            else if (ksize == 2) {
                if (pc == 0)            { r[0] = 0;      r[1] = 1;      }
                else if (pc == LEN - 1) { r[0] = TT - 2; r[1] = TT - 1; }
                else                    { r[0] = 2 * pc - 1; r[1] = 2 * pc; }
            } else {
                if (pc == 0)            { r[0] = 2; r[1] = 1; r[2] = 0; r[3] = 1; }
                else if (pc == LEN - 1) { r[0] = TT - 3; r[1] = TT - 2; r[2] = TT - 2; r[3] = TT - 1; }
                else                    { r[0] = 4*pc - 2; r[1] = 4*pc - 1; r[2] = 4*pc; r[3] = 4*pc + 1; }
            }
            #pragma unroll
            for (int j = 0; j < 4; ++j) { rg[i][j] = r[j]; ridx[i][j] = r[j] - (r0 - 2); }
            // closed-form nearest-upsample repeat counts (no integer divide)
            float c;
            if (ksize == 1)      c = 1.f;
            else if (ksize == 2) c = (pc == 1024 || pc == 2048) ? 1.f : 2.f;
            else                 c = ((pc & 255) == 0 && pc != 0) ? 3.f : 4.f;
            cw[i] = val[i] ? c : 0.f;
        }
        const float inv_k = 1.0f / (float)ksize;
        const float sscale = 0.125f * inv_k * inv_k;  // 1/sqrt(64) * pool-avg^2

        // scores on RAW (unscaled) pooled sums; feats in two 8-wide halves
        float S[4][4];
        #pragma unroll
        for (int i = 0; i < 4; ++i)
            #pragma unroll
            for (int j = 0; j < 4; ++j) S[i][j] = 0.f;

        for (int half = 0; half < 2; ++half) {
            float qf[4][8], kf[4][8];
            for (int i = 0; i < 4; ++i) {
                #pragma unroll
                for (int e = 0; e < 8; ++e) { qf[i][e] = 0.f; kf[i][e] = 0.f; }
                if (val[i])
                    for (int j = 0; j < ksize; ++j) {
                        int off = ridx[i][j] * STR + f0 + half * 8;
                        addu4(*(const uint4*)(qks + off), qf[i]);
                        addu4(*(const uint4*)(qks + PLQ + off), kf[i]);
                    }
            }
            #pragma unroll
            for (int i = 0; i < 4; ++i)
                #pragma unroll
                for (int j = 0; j < 4; ++j) {
                    float d = 0.f;
                    #pragma unroll
                    for (int e = 0; e < 8; ++e) d = fmaf(qf[i][e], kf[j][e], d);
                    S[i][j] += d;
                }
        }
        #pragma unroll
        for (int i = 0; i < 4; ++i)
            #pragma unroll
            for (int j = 0; j < 4; ++j) {
                float t = S[i][j];
                t += __shfl_xor(t, 1, 64);
                t += __shfl_xor(t, 2, 64);
                S[i][j] = t * sscale;
            }
        float P[4][4];
        #pragma unroll
        for (int i = 0; i < 4; ++i) {
            float m = fmaxf(fmaxf(S[i][0], S[i][1]), fmaxf(S[i][2], S[i][3]));
            float e0 = __expf(S[i][0] - m), e1 = __expf(S[i][1] - m);
            float e2 = __expf(S[i][2] - m), e3 = __expf(S[i][3] - m);
            float inv = 1.0f / (e0 + e1 + e2 + e3);
            P[i][0] = e0 * inv; P[i][1] = e1 * inv; P[i][2] = e2 * inv; P[i][3] = e3 * inv;
        }
        // PV from GLOBAL v (L1/L2-hot span) + gelu + repeat-count weighting
        for (int half = 0; half < 2; ++half) {
            float vf[4][8];
            for (int i = 0; i < 4; ++i) {
                #pragma unroll
                for (int e = 0; e < 8; ++e) vf[i][e] = 0.f;
                if (val[i])
                    for (int j = 0; j < ksize; ++j)
                        addu4(*(const uint4*)(vsrc + (size_t)rg[i][j] * DD + f0 + half * 8), vf[i]);
            }
            #pragma unroll
            for (int i = 0; i < 4; ++i) {
                if (!val[i]) continue;
                #pragma unroll
                for (int e = 0; e < 8; ++e) {
                    float o = P[i][0]*vf[0][e] + P[i][1]*vf[1][e]
                            + P[i][2]*vf[2][e] + P[i][3]*vf[3][e];
                    accL[half * 8 + e] += cw[i] * gelu_exact(o * inv_k);
                }
            }
        }
    }

    // ---- block reduction over the 16 window-units, one atomic per feat ----
    __syncthreads();   // all q/k LDS reads done; reuse LDS as scratch
    #pragma unroll
    for (int e = 0; e < 16; e += 4) {
        float4 d = {accL[e], accL[e+1], accL[e+2], accL[e+3]};
        *(float4*)(scratch + u * 256 + f0 + e) = d;
    }
    __syncthreads();
    float sum = 0.f;
    #pragma unroll
    for (int uu = 0; uu < 16; ++uu) sum += scratch[uu * 256 + tid];
    atomicAdd(&acc[b * DD + tid], sum);
}

// ======================= classifier head ===================================
__global__ __launch_bounds__(256)
void classifier_kernel(const float* __restrict__ acc,
                       const float* __restrict__ Wp,  const float* __restrict__ bp,
                       const float* __restrict__ Wc1, const float* __restrict__ bc1,
                       const float* __restrict__ Wc2, const float* __restrict__ bc2,
                       float* __restrict__ out)
{
    const int b = blockIdx.x;
    const int d = threadIdx.x;
    __shared__ float sm[256], sf[256], sh[256];

    sm[d] = acc[b * 256 + d] * (1.0f / 4096.0f);
    __syncthreads();

    float s = bp[d];
    for (int kk = 0; kk < 256; ++kk) s = fmaf(sm[kk], Wp[kk * 256 + d], s);
    sf[d] = s;
    __syncthreads();

    s = bc1[d];
    for (int kk = 0; kk < 256; ++kk) s = fmaf(sf[kk], Wc1[kk * 256 + d], s);
    sh[d] = fmaxf(s, 0.0f);
    __syncthreads();

    if (d < 7) {
        s = bc2[d];
        for (int kk = 0; kk < 256; ++kk) s = fmaf(sh[kk], Wc2[kk * 7 + d], s);
        out[b * 7 + d] = s;
    }
}

// ======================= launch ============================================
extern "C" void kernel_launch(void* const* d_in, const int* in_sizes, int n_in,
                              void* d_out, int out_size, void* d_ws, size_t ws_size,
                              hipStream_t stream)
{
    const float* x   = (const float*)d_in[0];
    const float* Wq  = (const float*)d_in[1];
    const float* bq  = (const float*)d_in[2];
    const float* Wk  = (const float*)d_in[3];
    const float* bk  = (const float*)d_in[4];
    const float* Wv  = (const float*)d_in[5];
    const float* bv  = (const float*)d_in[6];
    const float* Wp  = (const float*)d_in[7];
    const float* bp  = (const float*)d_in[8];
    const float* Wc1 = (const float*)d_in[9];
    const float* bc1 = (const float*)d_in[10];
    const float* Wc2 = (const float*)d_in[11];
    const float* bc2 = (const float*)d_in[12];
    float* out = (float*)d_out;

    const size_t plane = (size_t)BB * TT * DD;
    unsigned short* Q  = (unsigned short*)d_ws;
    unsigned short* K  = Q + plane;
    unsigned short* V  = K + plane;
    unsigned short* Xh = V + plane;
    unsigned short* Wt = Xh + plane;                 // [3][256][256] bf16
    float* acc = (float*)(Wt + 3 * 65536);

    prep_x_kernel<<<dim3(16384), 256, 0, stream>>>(x, Xh);
    prep_w_kernel<<<dim3(256, 3), 256, 0, stream>>>(Wq, Wk, Wv, Wt);
    (void)hipMemsetAsync(acc, 0, BB * DD * sizeof(float), stream);

    qkv_mfma_kernel<<<dim3(2, 1024, 3), 256, 0, stream>>>(
        Xh, Wt, bq, bk, bv, Q, K, V);

    attn_fused_kernel<<<dim3(128, BB), 256, 0, stream>>>(Q, K, V, acc);

    classifier_kernel<<<dim3(BB), 256, 0, stream>>>(acc, Wp, bp, Wc1, bc1, Wc2, bc2, out);
}

// Round 6
// 578.928 us; speedup vs baseline: 1.0717x; 1.0717x over previous
//
#include <hip/hip_runtime.h>

#define DD 256
#define TT 4096
#define BB 32

typedef __attribute__((ext_vector_type(8))) short short8;   // 8 bf16 (4 VGPR)
typedef __attribute__((ext_vector_type(4))) float floatx4;  // MFMA acc

// ---------- bf16 helpers (RNE via bit twiddle) ----------
__device__ __forceinline__ unsigned short f2bf(float f) {
    unsigned u = __builtin_bit_cast(unsigned, f);
    unsigned r = u + 0x7FFFu + ((u >> 16) & 1u);
    return (unsigned short)(r >> 16);
}
__device__ __forceinline__ unsigned pk2(float a, float b) {
    return (unsigned)f2bf(a) | ((unsigned)f2bf(b) << 16);
}
__device__ __forceinline__ float2 unpk(unsigned u) {
    float2 r;
    r.x = __builtin_bit_cast(float, u << 16);
    r.y = __builtin_bit_cast(float, u & 0xFFFF0000u);
    return r;
}

// ======================= weight prep: bf16 + transpose =====================
// Wt[z][n][k] bf16 (single term; round-5 verified absmax 9.8e-4).
__global__ void prep_w_kernel(const float* __restrict__ Wq,
                              const float* __restrict__ Wk,
                              const float* __restrict__ Wv,
                              unsigned short* __restrict__ Wt)
{
    const int z = blockIdx.y;
    const int k = blockIdx.x;
    const int n = threadIdx.x;
    const float* W = (z == 0) ? Wq : (z == 1) ? Wk : Wv;
    Wt[(size_t)z * 65536 + (size_t)n * 256 + k] = f2bf(W[k * 256 + n]);
}

// ======================= mega kernel =======================================
__device__ __forceinline__ float gelu_exact(float x) {
    return 0.5f * x * (1.0f + erff(x * 0.70710678118654752f));
}
__device__ __forceinline__ void addu4(uint4 d, float* f) {
    float2 t;
    t = unpk(d.x); f[0] += t.x; f[1] += t.y;
    t = unpk(d.y); f[2] += t.x; f[3] += t.y;
    t = unpk(d.z); f[4] += t.x; f[5] += t.y;
    t = unpk(d.w); f[6] += t.x; f[7] += t.y;
}

#define SPAN 32
#define NROW 34            // span + 2 leading ghost rows
#define STR  264           // bf16 LDS row stride (row*528B is 16B-aligned)
#define PLQ  (NROW * STR)  // one plane, elems

// Block = (span s, batch b), 256 threads = 4 waves.
// Phase 1: stage x rows r0-2..r0+31 as bf16 A in plane2.
// Phase 2: per-wave 64-col slab of q,k,v = A @ Wz (MFMA, B from global L2);
//          q,k -> planes 0,1; v held in regs, written over A after barrier.
// Phase 3: round-4 fused 3-scale attention from LDS planes.
// Phase 4: block reduction + one atomicAdd per feature.
__global__ __launch_bounds__(256, 3)
void mega_kernel(const float* __restrict__ x,
                 const unsigned short* __restrict__ Wt,
                 const float* __restrict__ bq, const float* __restrict__ bk,
                 const float* __restrict__ bv,
                 float* __restrict__ acc)
{
    __shared__ __align__(16) unsigned short qkvs[3 * PLQ];  // 53,856 B
    float* scratch = (float*)qkvs;                          // [16][256] overlay

    const int tid = threadIdx.x;
    const int s = blockIdx.x;          // span (0..127)
    const int b = blockIdx.y;
    const int r0 = s * SPAN;
    const float* xb = x + (size_t)b * TT * DD;

    // ---- phase 1: stage A = bf16(x[r0-2 .. r0+31]) into plane2 ----
    unsigned short* Am = qkvs + 2 * PLQ;   // [NROW][STR]
    #pragma unroll
    for (int it = 0; it < 9; ++it) {
        int flat = it * 256 + tid;                 // float4 index, need < 2176
        if (flat < NROW * 64) {
            int row = flat >> 6, c4 = flat & 63;
            int g = r0 - 2 + row;
            g = (g < 0) ? 0 : g;
            float4 d = *(const float4*)(xb + (size_t)g * DD + c4 * 4);
            *(uint2*)(Am + row * STR + c4 * 4) = make_uint2(pk2(d.x, d.y), pk2(d.z, d.w));
        }
    }
    __syncthreads();

    // ---- phase 2: q/k/v projections ----
    const int lane = tid & 63, wave = tid >> 6;
    const int l15 = lane & 15, lq = lane >> 4;
    const int colw = wave * 64;

    floatx4 vacc[3][4];    // v result held in regs until A is dead
    #pragma unroll
    for (int z = 0; z < 3; ++z) {
        const unsigned short* Wz = Wt + (size_t)z * 65536;
        const float* bias = (z == 0) ? bq : (z == 1) ? bk : bv;

        floatx4 cz[3][4];
        #pragma unroll
        for (int mt = 0; mt < 3; ++mt)
            #pragma unroll
            for (int nt = 0; nt < 4; ++nt)
                cz[mt][nt] = (floatx4){0.f, 0.f, 0.f, 0.f};

        #pragma unroll
        for (int kc = 0; kc < 8; ++kc) {
            short8 af[3];
            #pragma unroll
            for (int mt = 0; mt < 3; ++mt) {
                int arow = mt * 16 + l15;
                arow = (arow > 33) ? 33 : arow;    // mt=2 tail clamp (masked later)
                af[mt] = *(const short8*)(Am + arow * STR + kc * 32 + lq * 8);
            }
            #pragma unroll
            for (int nt = 0; nt < 4; ++nt) {
                short8 bf = *(const short8*)(Wz + (size_t)(colw + nt * 16 + l15) * 256 + kc * 32 + lq * 8);
                #pragma unroll
                for (int mt = 0; mt < 3; ++mt)
                    cz[mt][nt] = __builtin_amdgcn_mfma_f32_16x16x32_bf16(af[mt], bf, cz[mt][nt], 0, 0, 0);
            }
        }
        // add bias
        #pragma unroll
        for (int nt = 0; nt < 4; ++nt) {
            float bv_ = bias[colw + nt * 16 + l15];
            #pragma unroll
            for (int mt = 0; mt < 3; ++mt)
                #pragma unroll
                for (int r = 0; r < 4; ++r)
                    cz[mt][nt][r] += bv_;
        }
        if (z < 2) {
            // store q/k plane now (disjoint from A)
            unsigned short* Cs = qkvs + z * PLQ;
            #pragma unroll
            for (int mt = 0; mt < 3; ++mt)
                #pragma unroll
                for (int r = 0; r < 4; ++r) {
                    int row = mt * 16 + lq * 4 + r;
                    if (row < NROW) {
                        #pragma unroll
                        for (int nt = 0; nt < 4; ++nt)
                            Cs[row * STR + colw + nt * 16 + l15] = f2bf(cz[mt][nt][r]);
                    }
                }
        } else {
            #pragma unroll
            for (int mt = 0; mt < 3; ++mt)
                #pragma unroll
                for (int nt = 0; nt < 4; ++nt)
                    vacc[mt][nt] = cz[mt][nt];
        }
    }
    __syncthreads();   // all waves done reading A -> safe to overwrite with v
    {
        unsigned short* Cs = qkvs + 2 * PLQ;
        #pragma unroll
        for (int mt = 0; mt < 3; ++mt)
            #pragma unroll
            for (int r = 0; r < 4; ++r) {
                int row = mt * 16 + lq * 4 + r;
                if (row < NROW) {
                    #pragma unroll
                    for (int nt = 0; nt < 4; ++nt)
                        Cs[row * STR + colw + nt * 16 + l15] = f2bf(vacc[mt][nt][r]);
                }
            }
    }
    __syncthreads();

    // ---- phase 3: fused 3-scale attention (round-4 verified logic) ----
    const int slot = tid >> 2, lq4 = tid & 3;
    const int head = slot & 3, u = slot >> 2;     // u = 0..15
    int ksize, LEN, w; bool active = true;
    if (u < 8)       { ksize = 1; LEN = 4096; w = s * 8 + u; }
    else if (u < 12) { ksize = 2; LEN = 2049; w = s * 4 + (u - 8); }
    else if (u < 14) { ksize = 4; LEN = 1025; w = s * 2 + (u - 12); }
    else if (u == 14){ ksize = 2; LEN = 2049; w = 512; active = (s == 127); }
    else             { ksize = 4; LEN = 1025; w = 256; active = (s == 127); }

    const int f0 = head * 64 + lq4 * 16;
    float accL[16];
    #pragma unroll
    for (int i = 0; i < 16; ++i) accL[i] = 0.f;

    if (active) {
        int ridx[4][4]; float cw[4]; bool val[4];
        for (int i = 0; i < 4; ++i) {
            int p = w * 4 + i;
            val[i] = (p < LEN);
            int pc = val[i] ? p : 0;
            int r[4] = {0, 0, 0, 0};
            if (ksize == 1) { r[0] = pc; }
            else if (ksize == 2) {
                if (pc == 0)            { r[0] = 0;      r[1] = 1;      }
                else if (pc == LEN - 1) { r[0] = TT - 2; r[1] = TT - 1; }
                else                    { r[0] = 2 * pc - 1; r[1] = 2 * pc; }
            } else {
                if (pc == 0)            { r[0] = 2; r[1] = 1; r[2] = 0; r[3] = 1; }
                else if (pc == LEN - 1) { r[0] = TT - 3; r[1] = TT - 2; r[2] = TT - 2; r[3] = TT - 1; }
                else                    { r[0] = 4*pc - 2; r[1] = 4*pc - 1; r[2] = 4*pc; r[3] = 4*pc + 1; }
            }
            #pragma unroll
            for (int j = 0; j < 4; ++j) ridx[i][j] = r[j] - (r0 - 2);
            float c;
            if (ksize == 1)      c = 1.f;
            else if (ksize == 2) c = (pc == 1024 || pc == 2048) ? 1.f : 2.f;
            else                 c = ((pc & 255) == 0 && pc != 0) ? 3.f : 4.f;
            cw[i] = val[i] ? c : 0.f;
        }
        const float inv_k = 1.0f / (float)ksize;
        const float sscale = 0.125f * inv_k * inv_k;

        float S[4][4];
        #pragma unroll
        for (int i = 0; i < 4; ++i)
            #pragma unroll
            for (int j = 0; j < 4; ++j) S[i][j] = 0.f;

        for (int half = 0; half < 2; ++half) {
            float qf[4][8], kf[4][8];
            for (int i = 0; i < 4; ++i) {
                #pragma unroll
                for (int e = 0; e < 8; ++e) { qf[i][e] = 0.f; kf[i][e] = 0.f; }
                if (val[i])
                    for (int j = 0; j < ksize; ++j) {
                        int off = ridx[i][j] * STR + f0 + half * 8;
                        addu4(*(const uint4*)(qkvs + off), qf[i]);
                        addu4(*(const uint4*)(qkvs + PLQ + off), kf[i]);
                    }
            }
            #pragma unroll
            for (int i = 0; i < 4; ++i)
                #pragma unroll
                for (int j = 0; j < 4; ++j) {
                    float d = 0.f;
                    #pragma unroll
                    for (int e = 0; e < 8; ++e) d = fmaf(qf[i][e], kf[j][e], d);
                    S[i][j] += d;
                }
        }
        #pragma unroll
        for (int i = 0; i < 4; ++i)
            #pragma unroll
            for (int j = 0; j < 4; ++j) {
                float t = S[i][j];
                t += __shfl_xor(t, 1, 64);
                t += __shfl_xor(t, 2, 64);
                S[i][j] = t * sscale;
            }
        float P[4][4];
        #pragma unroll
        for (int i = 0; i < 4; ++i) {
            float m = fmaxf(fmaxf(S[i][0], S[i][1]), fmaxf(S[i][2], S[i][3]));
            float e0 = __expf(S[i][0] - m), e1 = __expf(S[i][1] - m);
            float e2 = __expf(S[i][2] - m), e3 = __expf(S[i][3] - m);
            float inv = 1.0f / (e0 + e1 + e2 + e3);
            P[i][0] = e0 * inv; P[i][1] = e1 * inv; P[i][2] = e2 * inv; P[i][3] = e3 * inv;
        }
        for (int half = 0; half < 2; ++half) {
            float vf[4][8];
            for (int i = 0; i < 4; ++i) {
                #pragma unroll
                for (int e = 0; e < 8; ++e) vf[i][e] = 0.f;
                if (val[i])
                    for (int j = 0; j < ksize; ++j) {
                        int off = ridx[i][j] * STR + f0 + half * 8;
                        addu4(*(const uint4*)(qkvs + 2 * PLQ + off), vf[i]);
                    }
            }
            #pragma unroll
            for (int i = 0; i < 4; ++i) {
                if (!val[i]) continue;
                #pragma unroll
                for (int e = 0; e < 8; ++e) {
                    float o = P[i][0]*vf[0][e] + P[i][1]*vf[1][e]
                            + P[i][2]*vf[2][e] + P[i][3]*vf[3][e];
                    accL[half * 8 + e] += cw[i] * gelu_exact(o * inv_k);
                }
            }
        }
    }

    // ---- phase 4: block reduction, one atomic per feature ----
    __syncthreads();
    #pragma unroll
    for (int e = 0; e < 16; e += 4) {
        float4 d = {accL[e], accL[e+1], accL[e+2], accL[e+3]};
        *(float4*)(scratch + u * 256 + f0 + e) = d;
    }
    __syncthreads();
    float sum = 0.f;
    #pragma unroll
    for (int uu = 0; uu < 16; ++uu) sum += scratch[uu * 256 + tid];
    atomicAdd(&acc[b * DD + tid], sum);
}

// ======================= classifier head ===================================
__global__ __launch_bounds__(256)
void classifier_kernel(const float* __restrict__ acc,
                       const float* __restrict__ Wp,  const float* __restrict__ bp,
                       const float* __restrict__ Wc1, const float* __restrict__ bc1,
                       const float* __restrict__ Wc2, const float* __restrict__ bc2,
                       float* __restrict__ out)
{
    const int b = blockIdx.x;
    const int d = threadIdx.x;
    __shared__ float sm[256], sf[256], sh[256];

    sm[d] = acc[b * 256 + d] * (1.0f / 4096.0f);
    __syncthreads();

    float s = bp[d];
    for (int kk = 0; kk < 256; ++kk) s = fmaf(sm[kk], Wp[kk * 256 + d], s);
    sf[d] = s;
    __syncthreads();

    s = bc1[d];
    for (int kk = 0; kk < 256; ++kk) s = fmaf(sf[kk], Wc1[kk * 256 + d], s);
    sh[d] = fmaxf(s, 0.0f);
    __syncthreads();

    if (d < 7) {
        s = bc2[d];
        for (int kk = 0; kk < 256; ++kk) s = fmaf(sh[kk], Wc2[kk * 7 + d], s);
        out[b * 7 + d] = s;
    }
}

// ======================= launch ============================================
extern "C" void kernel_launch(void* const* d_in, const int* in_sizes, int n_in,
                              void* d_out, int out_size, void* d_ws, size_t ws_size,
                              hipStream_t stream)
{
    const float* x   = (const float*)d_in[0];
    const float* Wq  = (const float*)d_in[1];
    const float* bq  = (const float*)d_in[2];
    const float* Wk  = (const float*)d_in[3];
    const float* bk  = (const float*)d_in[4];
    const float* Wv  = (const float*)d_in[5];
    const float* bv  = (const float*)d_in[6];
    const float* Wp  = (const float*)d_in[7];
    const float* bp  = (const float*)d_in[8];
    const float* Wc1 = (const float*)d_in[9];
    const float* bc1 = (const float*)d_in[10];
    const float* Wc2 = (const float*)d_in[11];
    const float* bc2 = (const float*)d_in[12];
    float* out = (float*)d_out;

    unsigned short* Wt = (unsigned short*)d_ws;      // [3][256][256] bf16
    float* acc = (float*)(Wt + 3 * 65536);           // [32][256] fp32

    prep_w_kernel<<<dim3(256, 3), 256, 0, stream>>>(Wq, Wk, Wv, Wt);
    (void)hipMemsetAsync(acc, 0, BB * DD * sizeof(float), stream);

    mega_kernel<<<dim3(128, BB), 256, 0, stream>>>(x, Wt, bq, bk, bv, acc);

    classifier_kernel<<<dim3(BB), 256, 0, stream>>>(acc, Wp, bp, Wc1, bc1, Wc2, bc2, out);
}

// Round 7
// 558.823 us; speedup vs baseline: 1.1103x; 1.0360x over previous
//
#include <hip/hip_runtime.h>

#define DD 256
#define TT 4096
#define BB 32

typedef __attribute__((ext_vector_type(8))) short short8;   // 8 bf16 (4 VGPR)
typedef __attribute__((ext_vector_type(4))) float floatx4;  // MFMA acc

// ---------- bf16 helpers (RNE via bit twiddle) ----------
__device__ __forceinline__ unsigned short f2bf(float f) {
    unsigned u = __builtin_bit_cast(unsigned, f);
    unsigned r = u + 0x7FFFu + ((u >> 16) & 1u);
    return (unsigned short)(r >> 16);
}
__device__ __forceinline__ unsigned pk2(float a, float b) {
    return (unsigned)f2bf(a) | ((unsigned)f2bf(b) << 16);
}
__device__ __forceinline__ float2 unpk(unsigned u) {
    float2 r;
    r.x = __builtin_bit_cast(float, u << 16);
    r.y = __builtin_bit_cast(float, u & 0xFFFF0000u);
    return r;
}

// ======================= weight prep: fragment-order bf16 ==================
// Wt laid out as [z][wave][kc][nt][lane][8] so mega's B-fragment loads are
// lane-contiguous (1 KB per wave instruction, 100% line utilization).
// Fragment semantics: value[j] = W[kc*32 + (lane>>4)*8 + j][wave*64 + nt*16 + (lane&15)]
__global__ __launch_bounds__(256)
void prep_w_kernel(const float* __restrict__ Wq,
                   const float* __restrict__ Wk,
                   const float* __restrict__ Wv,
                   unsigned short* __restrict__ Wt)
{
    const int z  = blockIdx.y;
    const int wv = blockIdx.x >> 3;    // wave slab 0..3
    const int kc = blockIdx.x & 7;     // 0..7
    const int nt = threadIdx.x >> 6;   // 0..3
    const int lane = threadIdx.x & 63;
    const int n  = wv * 64 + nt * 16 + (lane & 15);
    const int k0 = kc * 32 + (lane >> 4) * 8;
    const float* W = (z == 0) ? Wq : (z == 1) ? Wk : Wv;
    short8 o;
    #pragma unroll
    for (int j = 0; j < 8; ++j)
        o[j] = (short)f2bf(W[(size_t)(k0 + j) * 256 + n]);
    size_t idx = ((((size_t)z * 4 + wv) * 8 + kc) * 4 + nt) * 64 + lane;
    *(short8*)(Wt + idx * 8) = o;
}

// ======================= mega kernel =======================================
__device__ __forceinline__ float gelu_exact(float x) {
    return 0.5f * x * (1.0f + erff(x * 0.70710678118654752f));
}
__device__ __forceinline__ void addu4(uint4 d, float* f) {
    float2 t;
    t = unpk(d.x); f[0] += t.x; f[1] += t.y;
    t = unpk(d.y); f[2] += t.x; f[3] += t.y;
    t = unpk(d.z); f[4] += t.x; f[5] += t.y;
    t = unpk(d.w); f[6] += t.x; f[7] += t.y;
}

#define SPAN 32
#define NROW 34            // span + 2 leading ghost rows
#define STR  264           // bf16 LDS row stride (row*528B is 16B-aligned)
#define PLQ  (NROW * STR)  // one plane, elems

// Block = (span s, batch b), 256 threads = 4 waves.
// Phase 1: stage x rows r0-2..r0+31 as bf16 A in plane2.
// Phase 2: per-wave 64-col slab of q,k,v = A @ Wz (MFMA, B fragments from
//          global in fragment-order layout = coalesced); q,k -> planes 0,1;
//          v held in regs, written over A after barrier.
// Phase 3: fused 3-scale attention from LDS planes (r4-verified logic).
// Phase 4: block reduction + one atomicAdd per feature.
__global__ __launch_bounds__(256, 3)
void mega_kernel(const float* __restrict__ x,
                 const unsigned short* __restrict__ Wt,
                 const float* __restrict__ bq, const float* __restrict__ bk,
                 const float* __restrict__ bv,
                 float* __restrict__ acc)
{
    __shared__ __align__(16) unsigned short qkvs[3 * PLQ];  // 53,856 B
    float* scratch = (float*)qkvs;                          // [16][256] overlay

    const int tid = threadIdx.x;
    const int s = blockIdx.x;          // span (0..127)
    const int b = blockIdx.y;
    const int r0 = s * SPAN;
    const float* xb = x + (size_t)b * TT * DD;

    // ---- phase 1: stage A = bf16(x[r0-2 .. r0+31]) into plane2 ----
    unsigned short* Am = qkvs + 2 * PLQ;   // [NROW][STR]
    #pragma unroll
    for (int it = 0; it < 9; ++it) {
        int flat = it * 256 + tid;                 // float4 index, need < 2176
        if (flat < NROW * 64) {
            int row = flat >> 6, c4 = flat & 63;
            int g = r0 - 2 + row;
            g = (g < 0) ? 0 : g;
            float4 d = *(const float4*)(xb + (size_t)g * DD + c4 * 4);
            *(uint2*)(Am + row * STR + c4 * 4) = make_uint2(pk2(d.x, d.y), pk2(d.z, d.w));
        }
    }
    __syncthreads();

    // ---- phase 2: q/k/v projections ----
    const int lane = tid & 63, wave = tid >> 6;
    const int l15 = lane & 15, lq = lane >> 4;
    const int colw = wave * 64;

    floatx4 vacc[3][4];    // v result held in regs until A is dead
    #pragma unroll
    for (int z = 0; z < 3; ++z) {
        const unsigned short* Wzw = Wt + ((size_t)z * 4 + wave) * 16384;
        const float* bias = (z == 0) ? bq : (z == 1) ? bk : bv;

        floatx4 cz[3][4];
        #pragma unroll
        for (int mt = 0; mt < 3; ++mt)
            #pragma unroll
            for (int nt = 0; nt < 4; ++nt)
                cz[mt][nt] = (floatx4){0.f, 0.f, 0.f, 0.f};

        #pragma unroll
        for (int kc = 0; kc < 8; ++kc) {
            short8 af[3];
            #pragma unroll
            for (int mt = 0; mt < 3; ++mt) {
                int arow = mt * 16 + l15;
                arow = (arow > 33) ? 33 : arow;    // mt=2 tail clamp (masked later)
                af[mt] = *(const short8*)(Am + arow * STR + kc * 32 + lq * 8);
            }
            #pragma unroll
            for (int nt = 0; nt < 4; ++nt) {
                // fragment-order: lane-contiguous, fully coalesced
                short8 bf = *(const short8*)(Wzw + ((kc * 4 + nt) * 64 + lane) * 8);
                #pragma unroll
                for (int mt = 0; mt < 3; ++mt)
                    cz[mt][nt] = __builtin_amdgcn_mfma_f32_16x16x32_bf16(af[mt], bf, cz[mt][nt], 0, 0, 0);
            }
        }
        // add bias
        #pragma unroll
        for (int nt = 0; nt < 4; ++nt) {
            float bv_ = bias[colw + nt * 16 + l15];
            #pragma unroll
            for (int mt = 0; mt < 3; ++mt)
                #pragma unroll
                for (int r = 0; r < 4; ++r)
                    cz[mt][nt][r] += bv_;
        }
        if (z < 2) {
            // store q/k plane now (disjoint from A)
            unsigned short* Cs = qkvs + z * PLQ;
            #pragma unroll
            for (int mt = 0; mt < 3; ++mt)
                #pragma unroll
                for (int r = 0; r < 4; ++r) {
                    int row = mt * 16 + lq * 4 + r;
                    if (row < NROW) {
                        #pragma unroll
                        for (int nt = 0; nt < 4; ++nt)
                            Cs[row * STR + colw + nt * 16 + l15] = f2bf(cz[mt][nt][r]);
                    }
                }
        } else {
            #pragma unroll
            for (int mt = 0; mt < 3; ++mt)
                #pragma unroll
                for (int nt = 0; nt < 4; ++nt)
                    vacc[mt][nt] = cz[mt][nt];
        }
    }
    __syncthreads();   // all waves done reading A -> safe to overwrite with v
    {
        unsigned short* Cs = qkvs + 2 * PLQ;
        #pragma unroll
        for (int mt = 0; mt < 3; ++mt)
            #pragma unroll
            for (int r = 0; r < 4; ++r) {
                int row = mt * 16 + lq * 4 + r;
                if (row < NROW) {
                    #pragma unroll
                    for (int nt = 0; nt < 4; ++nt)
                        Cs[row * STR + colw + nt * 16 + l15] = f2bf(vacc[mt][nt][r]);
                }
            }
    }
    __syncthreads();

    // ---- phase 3: fused 3-scale attention (round-4 verified logic) ----
    const int slot = tid >> 2, lq4 = tid & 3;
    const int head = slot & 3, u = slot >> 2;     // u = 0..15
    int ksize, LEN, w; bool active = true;
    if (u < 8)       { ksize = 1; LEN = 4096; w = s * 8 + u; }
    else if (u < 12) { ksize = 2; LEN = 2049; w = s * 4 + (u - 8); }
    else if (u < 14) { ksize = 4; LEN = 1025; w = s * 2 + (u - 12); }
    else if (u == 14){ ksize = 2; LEN = 2049; w = 512; active = (s == 127); }
    else             { ksize = 4; LEN = 1025; w = 256; active = (s == 127); }

    const int f0 = head * 64 + lq4 * 16;
    float accL[16];
    #pragma unroll
    for (int i = 0; i < 16; ++i) accL[i] = 0.f;

    if (active) {
        int ridx[4][4]; float cw[4]; bool val[4];
        for (int i = 0; i < 4; ++i) {
            int p = w * 4 + i;
            val[i] = (p < LEN);
            int pc = val[i] ? p : 0;
            int r[4] = {0, 0, 0, 0};
            if (ksize == 1) { r[0] = pc; }
            else if (ksize == 2) {
                if (pc == 0)            { r[0] = 0;      r[1] = 1;      }
                else if (pc == LEN - 1) { r[0] = TT - 2; r[1] = TT - 1; }
                else                    { r[0] = 2 * pc - 1; r[1] = 2 * pc; }
            } else {
                if (pc == 0)            { r[0] = 2; r[1] = 1; r[2] = 0; r[3] = 1; }
                else if (pc == LEN - 1) { r[0] = TT - 3; r[1] = TT - 2; r[2] = TT - 2; r[3] = TT - 1; }
                else                    { r[0] = 4*pc - 2; r[1] = 4*pc - 1; r[2] = 4*pc; r[3] = 4*pc + 1; }
            }
            #pragma unroll
            for (int j = 0; j < 4; ++j) ridx[i][j] = r[j] - (r0 - 2);
            float c;
            if (ksize == 1)      c = 1.f;
            else if (ksize == 2) c = (pc == 1024 || pc == 2048) ? 1.f : 2.f;
            else                 c = ((pc & 255) == 0 && pc != 0) ? 3.f : 4.f;
            cw[i] = val[i] ? c : 0.f;
        }
        const float inv_k = 1.0f / (float)ksize;
        const float sscale = 0.125f * inv_k * inv_k;

        float S[4][4];
        #pragma unroll
        for (int i = 0; i < 4; ++i)
            #pragma unroll
            for (int j = 0; j < 4; ++j) S[i][j] = 0.f;

        for (int half = 0; half < 2; ++half) {
            float qf[4][8], kf[4][8];
            for (int i = 0; i < 4; ++i) {
                #pragma unroll
                for (int e = 0; e < 8; ++e) { qf[i][e] = 0.f; kf[i][e] = 0.f; }
                if (val[i])
                    for (int j = 0; j < ksize; ++j) {
                        int off = ridx[i][j] * STR + f0 + half * 8;
                        addu4(*(const uint4*)(qkvs + off), qf[i]);
                        addu4(*(const uint4*)(qkvs + PLQ + off), kf[i]);
                    }
            }
            #pragma unroll
            for (int i = 0; i < 4; ++i)
                #pragma unroll
                for (int j = 0; j < 4; ++j) {
                    float d = 0.f;
                    #pragma unroll
                    for (int e = 0; e < 8; ++e) d = fmaf(qf[i][e], kf[j][e], d);
                    S[i][j] += d;
                }
        }
        #pragma unroll
        for (int i = 0; i < 4; ++i)
            #pragma unroll
            for (int j = 0; j < 4; ++j) {
                float t = S[i][j];
                t += __shfl_xor(t, 1, 64);
                t += __shfl_xor(t, 2, 64);
                S[i][j] = t * sscale;
            }
        float P[4][4];
        #pragma unroll
        for (int i = 0; i < 4; ++i) {
            float m = fmaxf(fmaxf(S[i][0], S[i][1]), fmaxf(S[i][2], S[i][3]));
            float e0 = __expf(S[i][0] - m), e1 = __expf(S[i][1] - m);
            float e2 = __expf(S[i][2] - m), e3 = __expf(S[i][3] - m);
            float inv = 1.0f / (e0 + e1 + e2 + e3);
            P[i][0] = e0 * inv; P[i][1] = e1 * inv; P[i][2] = e2 * inv; P[i][3] = e3 * inv;
        }
        for (int half = 0; half < 2; ++half) {
            float vf[4][8];
            for (int i = 0; i < 4; ++i) {
                #pragma unroll
                for (int e = 0; e < 8; ++e) vf[i][e] = 0.f;
                if (val[i])
                    for (int j = 0; j < ksize; ++j) {
                        int off = ridx[i][j] * STR + f0 + half * 8;
                        addu4(*(const uint4*)(qkvs + 2 * PLQ + off), vf[i]);
                    }
            }
            #pragma unroll
            for (int i = 0; i < 4; ++i) {
                if (!val[i]) continue;
                #pragma unroll
                for (int e = 0; e < 8; ++e) {
                    float o = P[i][0]*vf[0][e] + P[i][1]*vf[1][e]
                            + P[i][2]*vf[2][e] + P[i][3]*vf[3][e];
                    accL[half * 8 + e] += cw[i] * gelu_exact(o * inv_k);
                }
            }
        }
    }

    // ---- phase 4: block reduction, one atomic per feature ----
    __syncthreads();
    #pragma unroll
    for (int e = 0; e < 16; e += 4) {
        float4 d = {accL[e], accL[e+1], accL[e+2], accL[e+3]};
        *(float4*)(scratch + u * 256 + f0 + e) = d;
    }
    __syncthreads();
    float sum = 0.f;
    #pragma unroll
    for (int uu = 0; uu < 16; ++uu) sum += scratch[uu * 256 + tid];
    atomicAdd(&acc[b * DD + tid], sum);
}

// ======================= classifier head (k-split, latency-pipelined) ======
// 1024 threads: thread = (d, slice); each slice sums 64 k with 4 independent
// accumulators so loads pipeline instead of chaining at L2 latency.
__global__ __launch_bounds__(1024)
void classifier_kernel(const float* __restrict__ acc,
                       const float* __restrict__ Wp,  const float* __restrict__ bp,
                       const float* __restrict__ Wc1, const float* __restrict__ bc1,
                       const float* __restrict__ Wc2, const float* __restrict__ bc2,
                       float* __restrict__ out)
{
    const int b = blockIdx.x;
    const int tid = threadIdx.x;
    const int d = tid & 255, sl = tid >> 8;     // slice 0..3
    __shared__ float sm[256], part[4][256], outs[7];

    if (tid < 256) sm[tid] = acc[b * 256 + tid] * (1.0f / 4096.0f);
    __syncthreads();

    // layer 1: fused = sm @ Wp + bp
    {
        const int k0 = sl * 64;
        float a0 = 0.f, a1 = 0.f, a2 = 0.f, a3 = 0.f;
        #pragma unroll
        for (int kk = 0; kk < 64; kk += 4) {
            a0 = fmaf(sm[k0+kk],   Wp[(size_t)(k0+kk)   * 256 + d], a0);
            a1 = fmaf(sm[k0+kk+1], Wp[(size_t)(k0+kk+1) * 256 + d], a1);
            a2 = fmaf(sm[k0+kk+2], Wp[(size_t)(k0+kk+2) * 256 + d], a2);
            a3 = fmaf(sm[k0+kk+3], Wp[(size_t)(k0+kk+3) * 256 + d], a3);
        }
        part[sl][d] = (a0 + a1) + (a2 + a3);
    }
    __syncthreads();
    if (sl == 0)
        sm[d] = part[0][d] + part[1][d] + part[2][d] + part[3][d] + bp[d];
    __syncthreads();

    // layer 2: h = relu(fused @ Wc1 + bc1)
    {
        const int k0 = sl * 64;
        float a0 = 0.f, a1 = 0.f, a2 = 0.f, a3 = 0.f;
        #pragma unroll
        for (int kk = 0; kk < 64; kk += 4) {
            a0 = fmaf(sm[k0+kk],   Wc1[(size_t)(k0+kk)   * 256 + d], a0);
            a1 = fmaf(sm[k0+kk+1], Wc1[(size_t)(k0+kk+1) * 256 + d], a1);
            a2 = fmaf(sm[k0+kk+2], Wc1[(size_t)(k0+kk+2) * 256 + d], a2);
            a3 = fmaf(sm[k0+kk+3], Wc1[(size_t)(k0+kk+3) * 256 + d], a3);
        }
        part[sl][d] = (a0 + a1) + (a2 + a3);
    }
    __syncthreads();
    if (sl == 0)
        sm[d] = fmaxf(part[0][d] + part[1][d] + part[2][d] + part[3][d] + bc1[d], 0.f);
    if (tid < 7) outs[tid] = 0.f;
    __syncthreads();

    // layer 3: logits = h @ Wc2 + bc2 (shuffle-reduce per wave, LDS combine)
    if (tid < 256) {
        float hv = sm[tid];
        float p[7];
        #pragma unroll
        for (int c = 0; c < 7; ++c) p[c] = hv * Wc2[tid * 7 + c];
        #pragma unroll
        for (int c = 0; c < 7; ++c) {
            p[c] += __shfl_xor(p[c], 1, 64);
            p[c] += __shfl_xor(p[c], 2, 64);
            p[c] += __shfl_xor(p[c], 4, 64);
            p[c] += __shfl_xor(p[c], 8, 64);
            p[c] += __shfl_xor(p[c], 16, 64);
            p[c] += __shfl_xor(p[c], 32, 64);
        }
        if ((tid & 63) == 0) {
            #pragma unroll
            for (int c = 0; c < 7; ++c) atomicAdd(&outs[c], p[c]);
        }
    }
    __syncthreads();
    if (tid < 7) out[b * 7 + tid] = outs[tid] + bc2[tid];
}

// ======================= launch ============================================
extern "C" void kernel_launch(void* const* d_in, const int* in_sizes, int n_in,
                              void* d_out, int out_size, void* d_ws, size_t ws_size,
                              hipStream_t stream)
{
    const float* x   = (const float*)d_in[0];
    const float* Wq  = (const float*)d_in[1];
    const float* bq  = (const float*)d_in[2];
    const float* Wk  = (const float*)d_in[3];
    const float* bk  = (const float*)d_in[4];
    const float* Wv  = (const float*)d_in[5];
    const float* bv  = (const float*)d_in[6];
    const float* Wp  = (const float*)d_in[7];
    const float* bp  = (const float*)d_in[8];
    const float* Wc1 = (const float*)d_in[9];
    const float* bc1 = (const float*)d_in[10];
    const float* Wc2 = (const float*)d_in[11];
    const float* bc2 = (const float*)d_in[12];
    float* out = (float*)d_out;

    unsigned short* Wt = (unsigned short*)d_ws;      // [3][4][8][4][64][8] bf16
    float* acc = (float*)(Wt + 3 * 65536);           // [32][256] fp32

    prep_w_kernel<<<dim3(32, 3), 256, 0, stream>>>(Wq, Wk, Wv, Wt);
    (void)hipMemsetAsync(acc, 0, BB * DD * sizeof(float), stream);

    mega_kernel<<<dim3(128, BB), 256, 0, stream>>>(x, Wt, bq, bk, bv, acc);

    classifier_kernel<<<dim3(BB), 1024, 0, stream>>>(acc, Wp, bp, Wc1, bc1, Wc2, bc2, out);
}